// Round 7
// baseline (1046.188 us; speedup 1.0000x reference)
//
#include <hip/hip_runtime.h>
#include <hip/hip_bf16.h>

#define N_NODES 12288
#define IN_DIM 256
#define OUT_DIM 128
#define NEG 0.01f
#define LOG2E 1.44269504088896340736f
#define NSPLIT 16
#define JSPAN (N_NODES / NSPLIT)     // 768
#define TJ 64
#define NT (JSPAN / TJ)              // 12

typedef __attribute__((ext_vector_type(8))) short short8;
typedef __attribute__((ext_vector_type(4))) float f32x4;
typedef __attribute__((ext_vector_type(4))) int i32x4;

__device__ __forceinline__ float fast_exp2(float x) {
#if __has_builtin(__builtin_amdgcn_exp2f)
  return __builtin_amdgcn_exp2f(x);
#else
  return exp2f(x);
#endif
}

// RNE float->bf16 (inputs always finite here)
__device__ __forceinline__ unsigned short f2bf(float x) {
  unsigned u = __float_as_uint(x);
  unsigned r = (u + 0x7FFFu + ((u >> 16) & 1u)) >> 16;
  return (unsigned short)r;
}

// ---------------- k1: proj + bf16 V^T + fused f/s + block-max(s) -------------
__global__ __launch_bounds__(256) void k1_proj(
    const float* __restrict__ X, const float* __restrict__ W,
    const float* __restrict__ bias, const float* __restrict__ phi,
    unsigned short* __restrict__ Vt, float* __restrict__ f,
    float* __restrict__ s, unsigned* __restrict__ smax) {
  __shared__ float Xs[32][40];    // [k][row]
  __shared__ float Ws[32][136];   // [k][col]
  __shared__ unsigned skey[8];
  const int t = threadIdx.x;
  const int i0 = blockIdx.x * 32;
  const int tx = t & 31, ty = t >> 5;   // cols 4tx.., rows 4ty..
  float acc[4][4] = {};
  for (int k0 = 0; k0 < IN_DIM; k0 += 32) {
    __syncthreads();
    {
      int r = t >> 3, kq = (t & 7) * 4;
      float4 xv = *(const float4*)&X[(size_t)(i0 + r) * IN_DIM + k0 + kq];
      Xs[kq + 0][r] = xv.x; Xs[kq + 1][r] = xv.y;
      Xs[kq + 2][r] = xv.z; Xs[kq + 3][r] = xv.w;
    }
#pragma unroll
    for (int q = 0; q < 4; ++q) {
      int idx = t + q * 256;
      int c = idx >> 3, kq = (idx & 7) * 4;
      float4 wv = *(const float4*)&W[(size_t)c * IN_DIM + k0 + kq];
      Ws[kq + 0][c] = wv.x; Ws[kq + 1][c] = wv.y;
      Ws[kq + 2][c] = wv.z; Ws[kq + 3][c] = wv.w;
    }
    __syncthreads();
#pragma unroll
    for (int kk = 0; kk < 32; ++kk) {
      float4 a = *(const float4*)&Xs[kk][ty * 4];
      float4 bv = *(const float4*)&Ws[kk][tx * 4];
      float av[4] = {a.x, a.y, a.z, a.w};
      float bw[4] = {bv.x, bv.y, bv.z, bv.w};
#pragma unroll
      for (int r = 0; r < 4; ++r)
#pragma unroll
        for (int c = 0; c < 4; ++c) acc[r][c] += av[r] * bw[c];
    }
  }
  float4 bv = *(const float4*)&bias[tx * 4];
  float bb[4] = {bv.x, bv.y, bv.z, bv.w};
  float4 p1 = *(const float4*)&phi[tx * 4];
  float4 p2 = *(const float4*)&phi[OUT_DIM + tx * 4];
  float p1a[4] = {p1.x, p1.y, p1.z, p1.w};
  float p2a[4] = {p2.x, p2.y, p2.z, p2.w};
  float fp[4], sp_[4];
#pragma unroll
  for (int r = 0; r < 4; ++r) {
    int i = i0 + ty * 4 + r;
    float o[4];
    fp[r] = 0.f; sp_[r] = 0.f;
#pragma unroll
    for (int c = 0; c < 4; ++c) {
      o[c] = acc[r][c] + bb[c];
      Vt[(size_t)(tx * 4 + c) * N_NODES + i] = f2bf(o[c]);
      fp[r] = __builtin_fmaf(o[c], p1a[c], fp[r]);
      sp_[r] = __builtin_fmaf(o[c], p2a[c], sp_[r]);
    }
  }
#pragma unroll
  for (int o = 16; o; o >>= 1) {
#pragma unroll
    for (int r = 0; r < 4; ++r) {
      fp[r] += __shfl_xor(fp[r], o);
      sp_[r] += __shfl_xor(sp_[r], o);
    }
  }
  if (tx == 0) {
    unsigned kmax = 0;
#pragma unroll
    for (int r = 0; r < 4; ++r) {
      int i = i0 + ty * 4 + r;
      f[i] = fp[r]; s[i] = sp_[r];
      unsigned u = __float_as_uint(sp_[r]);
      unsigned key = (u & 0x80000000u) ? ~u : (u | 0x80000000u);
      kmax = max(kmax, key);
    }
    skey[ty] = kmax;
  }
  __syncthreads();
  if (t == 0) {
    unsigned kmax = skey[0];
#pragma unroll
    for (int q = 1; q < 8; ++q) kmax = max(kmax, skey[q]);
    atomicMax(smax, kmax);
  }
}

// ---------------- k3: fused mask/softmax-numerator + P@V (bf16 MFMA) ---------
// grid = 192 row-blocks x NSPLIT=16; block = 256 thr (4 waves), barrier-free.
// TLP-first: 3072 blocks (12/CU queued), low-VGPR body (~72) -> ~7 blocks/CU
// resident. sp = blockIdx&15 aligns each Vt/s slice to one XCD's L2 and
// partitions adj columns across XCDs with no duplication.
__global__ __launch_bounds__(256) void k3_attn(
    const int* __restrict__ adj, const unsigned short* __restrict__ Vt,
    const float* __restrict__ f, const float* __restrict__ s,
    const unsigned* __restrict__ smaxk,
    float* __restrict__ pacc, float* __restrict__ pden) {
  __shared__ float s_lds[JSPAN];              // 3 KB, read-only after prologue
  const int t = threadIdx.x;
  const int sp = blockIdx.x & (NSPLIT - 1);
  const int rb = blockIdx.x >> 4;
  const int j0g = sp * JSPAN;
  const int w = t >> 6, l = t & 63;
  const int m = l & 15, slot = l >> 4;
  const int row_g = rb * 64 + w * 16 + m;     // P row this lane computes
  if (t < JSPAN / 4) {
    *(float4*)&s_lds[t * 4] = *(const float4*)&s[j0g + t * 4];
  }
  unsigned key = *smaxk;
  unsigned ku = (key & 0x80000000u) ? (key ^ 0x80000000u) : ~key;
  const float smaxv = __uint_as_float(ku);
  const float fi = f[row_g];
  const float xm = fi + smaxv;
  const float mrow = fmaxf(xm, NEG * xm);     // >= all sims in row (monotone lrelu)
  const float em = mrow * LOG2E;
  const int diag_g = row_g - j0g;             // local self-loop col (may be OOR)
  float dsum = 0.f;
  f32x4 acc[8] = {};                          // nt = 0..7 (full d=128 per wave)
  const int* adjp = adj + (size_t)row_g * N_NODES + j0g + 8 * slot;
  const unsigned short* vtp = Vt + (size_t)m * N_NODES + j0g + 8 * slot;
  i32x4 aA[4], aB[4];

#define ADJ_LOAD(SET, TT) { int _o = (TT) * TJ;                       \
    SET[0] = *(const i32x4*)(adjp + _o);                              \
    SET[1] = *(const i32x4*)(adjp + _o + 4);                          \
    SET[2] = *(const i32x4*)(adjp + _o + 32);                         \
    SET[3] = *(const i32x4*)(adjp + _o + 36); }

  ADJ_LOAD(aA, 0);
  ADJ_LOAD(aB, 1);
  __syncthreads();   // s_lds ready (one-time, prologue only)

#define ITER(TT, SET) {                                                     \
    short8 b0[8], b1[8];                                                    \
    _Pragma("unroll")                                                       \
    for (int nt = 0; nt < 8; ++nt)                                          \
      b0[nt] = *(const short8*)(vtp + (size_t)nt * 16 * N_NODES + (TT) * TJ); \
    _Pragma("unroll")                                                       \
    for (int nt = 0; nt < 8; ++nt)                                          \
      b1[nt] = *(const short8*)(vtp + (size_t)nt * 16 * N_NODES + (TT) * TJ + 32); \
    short8 af0, af1;                                                        \
    _Pragma("unroll")                                                       \
    for (int c = 0; c < 2; ++c) {                                           \
      int jb = (TT) * TJ + 32 * c + 8 * slot;                               \
      float4 sv0 = *(const float4*)&s_lds[jb];                              \
      float4 sv1 = *(const float4*)&s_lds[jb + 4];                          \
      int av[8] = {SET[2*c].x, SET[2*c].y, SET[2*c].z, SET[2*c].w,          \
                   SET[2*c+1].x, SET[2*c+1].y, SET[2*c+1].z, SET[2*c+1].w}; \
      float sva[8] = {sv0.x, sv0.y, sv0.z, sv0.w, sv1.x, sv1.y, sv1.z, sv1.w}; \
      _Pragma("unroll")                                                     \
      for (int q = 0; q < 8; ++q) {                                         \
        float x = fi + sva[q];                                              \
        float xl = fmaxf(x, NEG * x);                                       \
        float e = fast_exp2(__builtin_fmaf(xl, LOG2E, -em));                \
        bool edge = (av[q] > 0) || ((jb + q) == diag_g);                    \
        float p = edge ? e : 0.f;                                           \
        dsum += p;                                                          \
        if (c == 0) af0[q] = (short)f2bf(p); else af1[q] = (short)f2bf(p);  \
      }                                                                     \
    }                                                                       \
    ADJ_LOAD(SET, ((TT) + 2 < NT) ? (TT) + 2 : NT - 1);  /* last vmem issue */ \
    _Pragma("unroll")                                                       \
    for (int nt = 0; nt < 8; ++nt)                                          \
      acc[nt] = __builtin_amdgcn_mfma_f32_16x16x32_bf16(af0, b0[nt], acc[nt], 0, 0, 0); \
    _Pragma("unroll")                                                       \
    for (int nt = 0; nt < 8; ++nt)                                          \
      acc[nt] = __builtin_amdgcn_mfma_f32_16x16x32_bf16(af1, b1[nt], acc[nt], 0, 0, 0); \
  }

  for (int tb = 0; tb < NT; tb += 2) {
    ITER(tb, aA);
    ITER(tb + 1, aB);
  }
#undef ITER
#undef ADJ_LOAD

  // row denominator: reduce over the 4 k-slot lanes {m, m+16, m+32, m+48}
  dsum += __shfl_xor(dsum, 16);
  dsum += __shfl_xor(dsum, 32);
  if (l < 16) pden[sp * N_NODES + rb * 64 + w * 16 + l] = dsum;
  // C write: out-row = rb*64 + 16w + slot*4 + r, out-col = nt*16 + m
  float* pa = pacc + (size_t)sp * N_NODES * OUT_DIM;
#pragma unroll
  for (int nt = 0; nt < 8; ++nt)
#pragma unroll
    for (int r = 0; r < 4; ++r) {
      int ii = rb * 64 + w * 16 + slot * 4 + r;
      pa[(size_t)ii * OUT_DIM + nt * 16 + m] = acc[nt][r];
    }
}

// ---------------- k4: combine partials, divide, final leaky_relu -------------
__global__ __launch_bounds__(256) void k4_comb(
    const float* __restrict__ pacc, const float* __restrict__ pden,
    float* __restrict__ out) {
  int idx = blockIdx.x * 256 + threadIdx.x;
  int i = idx >> 7;
  float v = 0.f, den = 0.f;
#pragma unroll
  for (int spp = 0; spp < NSPLIT; ++spp) {
    v += pacc[(size_t)spp * N_NODES * OUT_DIM + idx];
    den += pden[spp * N_NODES + i];
  }
  float o = v / den;
  out[idx] = fmaxf(o, NEG * o);
}

extern "C" void kernel_launch(void* const* d_in, const int* in_sizes, int n_in,
                              void* d_out, int out_size, void* d_ws, size_t ws_size,
                              hipStream_t stream) {
  const int* adj = (const int*)d_in[0];
  const float* X = (const float*)d_in[1];
  const float* W = (const float*)d_in[2];
  const float* b = (const float*)d_in[3];
  const float* phi = (const float*)d_in[4];
  float* out = (float*)d_out;
  char* ws = (char*)d_ws;
  // ws layout (bytes, 16-aligned):
  unsigned short* Vt = (unsigned short*)(ws);            // 128*12288*2 = 3,145,728
  float* fv   = (float*)(ws + 3145728);                  // 49,152
  float* sv   = (float*)(ws + 3194880);                  // 49,152
  unsigned* smax = (unsigned*)(ws + 3244032);            // 16
  float* pden = (float*)(ws + 3244048);                  // 16*12288*4 = 786,432
  float* pacc = (float*)(ws + 4030480);                  // 16*12288*128*4 = 100,663,296

  hipMemsetAsync(smax, 0, 4, stream);
  hipLaunchKernelGGL(k1_proj, dim3(N_NODES / 32), dim3(256), 0, stream,
                     X, W, b, phi, Vt, fv, sv, smax);
  hipLaunchKernelGGL(k3_attn, dim3((N_NODES / 64) * NSPLIT), dim3(256), 0, stream,
                     adj, Vt, fv, sv, smax, pacc, pden);
  hipLaunchKernelGGL(k4_comb, dim3((N_NODES * OUT_DIM) / 256), dim3(256), 0, stream,
                     pacc, pden, out);
}

// Round 9
// 866.316 us; speedup vs baseline: 1.2076x; 1.2076x over previous
//
#include <hip/hip_runtime.h>
#include <hip/hip_bf16.h>

#define N_NODES 12288
#define IN_DIM 256
#define OUT_DIM 128
#define NEG 0.01f
#define LOG2E 1.44269504088896340736f
#define NSPLIT 16
#define JSPAN (N_NODES / NSPLIT)     // 768
#define TJ 64
#define NT (JSPAN / TJ)              // 12

typedef __attribute__((ext_vector_type(8))) short short8;
typedef __attribute__((ext_vector_type(4))) float f32x4;
typedef __attribute__((ext_vector_type(4))) int i32x4;

__device__ __forceinline__ float fast_exp2(float x) {
#if __has_builtin(__builtin_amdgcn_exp2f)
  return __builtin_amdgcn_exp2f(x);
#else
  return exp2f(x);
#endif
}

// RNE float->bf16 (inputs always finite here)
__device__ __forceinline__ unsigned short f2bf(float x) {
  unsigned u = __float_as_uint(x);
  unsigned r = (u + 0x7FFFu + ((u >> 16) & 1u)) >> 16;
  return (unsigned short)r;
}

// ---------------- k1: proj + bf16 V^T + fused f/s + block-max(s) -------------
__global__ __launch_bounds__(256) void k1_proj(
    const float* __restrict__ X, const float* __restrict__ W,
    const float* __restrict__ bias, const float* __restrict__ phi,
    unsigned short* __restrict__ Vt, float* __restrict__ f,
    float* __restrict__ s, unsigned* __restrict__ smax) {
  __shared__ float Xs[32][40];    // [k][row]
  __shared__ float Ws[32][136];   // [k][col]
  __shared__ unsigned skey[8];
  const int t = threadIdx.x;
  const int i0 = blockIdx.x * 32;
  const int tx = t & 31, ty = t >> 5;   // cols 4tx.., rows 4ty..
  float acc[4][4] = {};
  for (int k0 = 0; k0 < IN_DIM; k0 += 32) {
    __syncthreads();
    {
      int r = t >> 3, kq = (t & 7) * 4;
      float4 xv = *(const float4*)&X[(size_t)(i0 + r) * IN_DIM + k0 + kq];
      Xs[kq + 0][r] = xv.x; Xs[kq + 1][r] = xv.y;
      Xs[kq + 2][r] = xv.z; Xs[kq + 3][r] = xv.w;
    }
#pragma unroll
    for (int q = 0; q < 4; ++q) {
      int idx = t + q * 256;
      int c = idx >> 3, kq = (idx & 7) * 4;
      float4 wv = *(const float4*)&W[(size_t)c * IN_DIM + k0 + kq];
      Ws[kq + 0][c] = wv.x; Ws[kq + 1][c] = wv.y;
      Ws[kq + 2][c] = wv.z; Ws[kq + 3][c] = wv.w;
    }
    __syncthreads();
#pragma unroll
    for (int kk = 0; kk < 32; ++kk) {
      float4 a = *(const float4*)&Xs[kk][ty * 4];
      float4 bv = *(const float4*)&Ws[kk][tx * 4];
      float av[4] = {a.x, a.y, a.z, a.w};
      float bw[4] = {bv.x, bv.y, bv.z, bv.w};
#pragma unroll
      for (int r = 0; r < 4; ++r)
#pragma unroll
        for (int c = 0; c < 4; ++c) acc[r][c] += av[r] * bw[c];
    }
  }
  float4 bv = *(const float4*)&bias[tx * 4];
  float bb[4] = {bv.x, bv.y, bv.z, bv.w};
  float4 p1 = *(const float4*)&phi[tx * 4];
  float4 p2 = *(const float4*)&phi[OUT_DIM + tx * 4];
  float p1a[4] = {p1.x, p1.y, p1.z, p1.w};
  float p2a[4] = {p2.x, p2.y, p2.z, p2.w};
  float fp[4], sp_[4];
#pragma unroll
  for (int r = 0; r < 4; ++r) {
    int i = i0 + ty * 4 + r;
    float o[4];
    fp[r] = 0.f; sp_[r] = 0.f;
#pragma unroll
    for (int c = 0; c < 4; ++c) {
      o[c] = acc[r][c] + bb[c];
      Vt[(size_t)(tx * 4 + c) * N_NODES + i] = f2bf(o[c]);
      fp[r] = __builtin_fmaf(o[c], p1a[c], fp[r]);
      sp_[r] = __builtin_fmaf(o[c], p2a[c], sp_[r]);
    }
  }
#pragma unroll
  for (int o = 16; o; o >>= 1) {
#pragma unroll
    for (int r = 0; r < 4; ++r) {
      fp[r] += __shfl_xor(fp[r], o);
      sp_[r] += __shfl_xor(sp_[r], o);
    }
  }
  if (tx == 0) {
    unsigned kmax = 0;
#pragma unroll
    for (int r = 0; r < 4; ++r) {
      int i = i0 + ty * 4 + r;
      f[i] = fp[r]; s[i] = sp_[r];
      unsigned u = __float_as_uint(sp_[r]);
      unsigned key = (u & 0x80000000u) ? ~u : (u | 0x80000000u);
      kmax = max(kmax, key);
    }
    skey[ty] = kmax;
  }
  __syncthreads();
  if (t == 0) {
    unsigned kmax = skey[0];
#pragma unroll
    for (int q = 1; q < 8; ++q) kmax = max(kmax, skey[q]);
    atomicMax(smax, kmax);
  }
}

// ---------------- k3: fused mask/softmax-numerator + P@V (bf16 MFMA) ---------
// grid = 192 row-blocks x NSPLIT=16; block = 256 thr (4 waves).
// Vt tile (128 x 64 bf16 = 16KB) staged per block into double-buffered LDS
// via global_load_lds width=16 (coalesced 8-lines/instr; shared by all 4
// waves -> kills the per-wave 16-line gather storm of rounds 3-7).
// Bank conflicts: LDS dest linear, global SOURCE chunk XOR-swizzled
// (chunk ^= d&7), ds_read applies the same XOR (rule #21 both-sides).
// One __syncthreads per iter; stage issued AFTER the barrier (drain covers
// only last iter's loads). adj keeps distance-2 register prefetch.
__global__ __launch_bounds__(256) void k3_attn(
    const int* __restrict__ adj, const unsigned short* __restrict__ Vt,
    const float* __restrict__ f, const float* __restrict__ s,
    const unsigned* __restrict__ smaxk,
    float* __restrict__ pacc, float* __restrict__ pden) {
  __shared__ float s_lds[JSPAN];                            // 3 KB
  __shared__ __align__(16) unsigned short vbuf[2][128 * TJ]; // 32 KB dbuf
  const int t = threadIdx.x;
  const int sp = blockIdx.x & (NSPLIT - 1);
  const int rb = blockIdx.x >> 4;
  const int j0g = sp * JSPAN;
  const int w = t >> 6, l = t & 63;
  const int m = l & 15, slot = l >> 4;
  const int row_g = rb * 64 + w * 16 + m;     // P row this lane computes
  if (t < JSPAN / 4) {
    *(float4*)&s_lds[t * 4] = *(const float4*)&s[j0g + t * 4];
  }
  unsigned key = *smaxk;
  unsigned ku = (key & 0x80000000u) ? (key ^ 0x80000000u) : ~key;
  const float smaxv = __uint_as_float(ku);
  const float fi = f[row_g];
  const float xm = fi + smaxv;
  const float mrow = fmaxf(xm, NEG * xm);     // >= all sims in row (monotone lrelu)
  const float em = mrow * LOG2E;
  const int diag_g = row_g - j0g;             // local self-loop col (may be OOR)
  float dsum = 0.f;
  f32x4 acc[8] = {};                          // nt = 0..7 (full d=128 per wave)
  const int* adjp = adj + (size_t)row_g * N_NODES + j0g + 8 * slot;
  // staging mapping: thread t -> rows (t>>3)+32k, chunk (t&7), source-swizzled
  const int srow = t >> 3, schunk = t & 7;
  const int xsw = schunk ^ (srow & 7);        // source chunk swizzle
  const unsigned short* vt_src = Vt + (size_t)srow * N_NODES + j0g + xsw * 8;
  // fragment read offsets (ushort units), same XOR on the read side:
  // lane (n = l&15, s = slot) reads d-row (16nt+n), chunk' = (4cc+s)^(n&7)
  const int off0 = m * TJ + ((slot) ^ (m & 7)) * 8;       // cc=0 half
  const int off1 = m * TJ + ((4 + slot) ^ (m & 7)) * 8;   // cc=1 half
  i32x4 aA[4], aB[4];

#define ADJ_LOAD(SET, TT) { int _o = (TT) * TJ;                       \
    SET[0] = *(const i32x4*)(adjp + _o);                              \
    SET[1] = *(const i32x4*)(adjp + _o + 4);                          \
    SET[2] = *(const i32x4*)(adjp + _o + 32);                         \
    SET[3] = *(const i32x4*)(adjp + _o + 36); }

#define STAGE(BB, TT) { const unsigned short* _s = vt_src + (TT) * TJ;      \
    unsigned short* _d = &vbuf[BB][t * 8];                                  \
    __builtin_amdgcn_global_load_lds(_s,                    _d,        16, 0, 0); \
    __builtin_amdgcn_global_load_lds(_s + 32 * N_NODES,     _d + 2048, 16, 0, 0); \
    __builtin_amdgcn_global_load_lds(_s + 64 * N_NODES,     _d + 4096, 16, 0, 0); \
    __builtin_amdgcn_global_load_lds(_s + 96 * N_NODES,     _d + 6144, 16, 0, 0); }

  STAGE(0, 0);
  ADJ_LOAD(aA, 0);
  ADJ_LOAD(aB, 1);

#define ITER(TT, SET) {                                                     \
    __syncthreads();  /* drains stage(TT) + finishes prior frag reads */    \
    STAGE(((TT) + 1) & 1, ((TT) + 1 < NT) ? (TT) + 1 : NT - 1);             \
    const unsigned short* rdp = &vbuf[(TT) & 1][0];                         \
    short8 b0[8], b1[8];                                                    \
    _Pragma("unroll")                                                       \
    for (int nt = 0; nt < 8; ++nt)                                          \
      b0[nt] = *(const short8*)(rdp + off0 + nt * 16 * TJ);                 \
    _Pragma("unroll")                                                       \
    for (int nt = 0; nt < 8; ++nt)                                          \
      b1[nt] = *(const short8*)(rdp + off1 + nt * 16 * TJ);                 \
    short8 af0, af1;                                                        \
    _Pragma("unroll")                                                       \
    for (int c = 0; c < 2; ++c) {                                           \
      int jb = (TT) * TJ + 32 * c + 8 * slot;                               \
      float4 sv0 = *(const float4*)&s_lds[jb];                              \
      float4 sv1 = *(const float4*)&s_lds[jb + 4];                          \
      int av[8] = {SET[2*c].x, SET[2*c].y, SET[2*c].z, SET[2*c].w,          \
                   SET[2*c+1].x, SET[2*c+1].y, SET[2*c+1].z, SET[2*c+1].w}; \
      float sva[8] = {sv0.x, sv0.y, sv0.z, sv0.w, sv1.x, sv1.y, sv1.z, sv1.w}; \
      _Pragma("unroll")                                                     \
      for (int q = 0; q < 8; ++q) {                                         \
        float x = fi + sva[q];                                              \
        float xl = fmaxf(x, NEG * x);                                       \
        float e = fast_exp2(__builtin_fmaf(xl, LOG2E, -em));                \
        bool edge = (av[q] > 0) || ((jb + q) == diag_g);                    \
        float p = edge ? e : 0.f;                                           \
        dsum += p;                                                          \
        if (c == 0) af0[q] = (short)f2bf(p); else af1[q] = (short)f2bf(p);  \
      }                                                                     \
    }                                                                       \
    ADJ_LOAD(SET, ((TT) + 2 < NT) ? (TT) + 2 : NT - 1);                     \
    _Pragma("unroll")                                                       \
    for (int nt = 0; nt < 8; ++nt)                                          \
      acc[nt] = __builtin_amdgcn_mfma_f32_16x16x32_bf16(af0, b0[nt], acc[nt], 0, 0, 0); \
    _Pragma("unroll")                                                       \
    for (int nt = 0; nt < 8; ++nt)                                          \
      acc[nt] = __builtin_amdgcn_mfma_f32_16x16x32_bf16(af1, b1[nt], acc[nt], 0, 0, 0); \
  }

  for (int tb = 0; tb < NT; tb += 2) {
    ITER(tb, aA);
    ITER(tb + 1, aB);
  }
#undef ITER
#undef STAGE
#undef ADJ_LOAD

  // row denominator: reduce over the 4 k-slot lanes {m, m+16, m+32, m+48}
  dsum += __shfl_xor(dsum, 16);
  dsum += __shfl_xor(dsum, 32);
  if (l < 16) pden[sp * N_NODES + rb * 64 + w * 16 + l] = dsum;
  // C write: out-row = rb*64 + 16w + slot*4 + r, out-col = nt*16 + m
  float* pa = pacc + (size_t)sp * N_NODES * OUT_DIM;
#pragma unroll
  for (int nt = 0; nt < 8; ++nt)
#pragma unroll
    for (int r = 0; r < 4; ++r) {
      int ii = rb * 64 + w * 16 + slot * 4 + r;
      pa[(size_t)ii * OUT_DIM + nt * 16 + m] = acc[nt][r];
    }
}

// ---------------- k4: combine partials, divide, final leaky_relu -------------
__global__ __launch_bounds__(256) void k4_comb(
    const float* __restrict__ pacc, const float* __restrict__ pden,
    float* __restrict__ out) {
  int idx = blockIdx.x * 256 + threadIdx.x;
  int i = idx >> 7;
  float v = 0.f, den = 0.f;
#pragma unroll
  for (int spp = 0; spp < NSPLIT; ++spp) {
    v += pacc[(size_t)spp * N_NODES * OUT_DIM + idx];
    den += pden[spp * N_NODES + i];
  }
  float o = v / den;
  out[idx] = fmaxf(o, NEG * o);
}

extern "C" void kernel_launch(void* const* d_in, const int* in_sizes, int n_in,
                              void* d_out, int out_size, void* d_ws, size_t ws_size,
                              hipStream_t stream) {
  const int* adj = (const int*)d_in[0];
  const float* X = (const float*)d_in[1];
  const float* W = (const float*)d_in[2];
  const float* b = (const float*)d_in[3];
  const float* phi = (const float*)d_in[4];
  float* out = (float*)d_out;
  char* ws = (char*)d_ws;
  // ws layout (bytes, 16-aligned):
  unsigned short* Vt = (unsigned short*)(ws);            // 128*12288*2 = 3,145,728
  float* fv   = (float*)(ws + 3145728);                  // 49,152
  float* sv   = (float*)(ws + 3194880);                  // 49,152
  unsigned* smax = (unsigned*)(ws + 3244032);            // 16
  float* pden = (float*)(ws + 3244048);                  // 16*12288*4 = 786,432
  float* pacc = (float*)(ws + 4030480);                  // 16*12288*128*4 = 100,663,296

  hipMemsetAsync(smax, 0, 4, stream);
  hipLaunchKernelGGL(k1_proj, dim3(N_NODES / 32), dim3(256), 0, stream,
                     X, W, b, phi, Vt, fv, sv, smax);
  hipLaunchKernelGGL(k3_attn, dim3((N_NODES / 64) * NSPLIT), dim3(256), 0, stream,
                     adj, Vt, fv, sv, smax, pacc, pden);
  hipLaunchKernelGGL(k4_comb, dim3((N_NODES * OUT_DIM) / 256), dim3(256), 0, stream,
                     pacc, pden, out);
}

// Round 14
// 853.495 us; speedup vs baseline: 1.2258x; 1.0150x over previous
//
#include <hip/hip_runtime.h>
#include <hip/hip_bf16.h>

#define N_NODES 12288
#define IN_DIM 256
#define OUT_DIM 128
#define NEG 0.01f
#define LOG2E 1.44269504088896340736f
#define NSPLIT 8
#define JSPAN (N_NODES / NSPLIT)     // 1536
#define TJ 64
#define NT (JSPAN / TJ)              // 24

typedef __attribute__((ext_vector_type(8))) short short8;
typedef __attribute__((ext_vector_type(4))) float f32x4;
typedef __attribute__((ext_vector_type(4))) int i32x4;

__device__ __forceinline__ float fast_exp2(float x) {
#if __has_builtin(__builtin_amdgcn_exp2f)
  return __builtin_amdgcn_exp2f(x);
#else
  return exp2f(x);
#endif
}

// RNE float->bf16 (inputs always finite here)
__device__ __forceinline__ unsigned short f2bf(float x) {
  unsigned u = __float_as_uint(x);
  unsigned r = (u + 0x7FFFu + ((u >> 16) & 1u)) >> 16;
  return (unsigned short)r;
}

// ---------------- k1: proj + bf16 V^T + fused f/s + block-max(s) -------------
__global__ __launch_bounds__(256) void k1_proj(
    const float* __restrict__ X, const float* __restrict__ W,
    const float* __restrict__ bias, const float* __restrict__ phi,
    unsigned short* __restrict__ Vt, float* __restrict__ f,
    float* __restrict__ s, unsigned* __restrict__ smax) {
  __shared__ float Xs[32][40];    // [k][row]
  __shared__ float Ws[32][136];   // [k][col]
  __shared__ unsigned skey[8];
  const int t = threadIdx.x;
  const int i0 = blockIdx.x * 32;
  const int tx = t & 31, ty = t >> 5;   // cols 4tx.., rows 4ty..
  float acc[4][4] = {};
  for (int k0 = 0; k0 < IN_DIM; k0 += 32) {
    __syncthreads();
    {
      int r = t >> 3, kq = (t & 7) * 4;
      float4 xv = *(const float4*)&X[(size_t)(i0 + r) * IN_DIM + k0 + kq];
      Xs[kq + 0][r] = xv.x; Xs[kq + 1][r] = xv.y;
      Xs[kq + 2][r] = xv.z; Xs[kq + 3][r] = xv.w;
    }
#pragma unroll
    for (int q = 0; q < 4; ++q) {
      int idx = t + q * 256;
      int c = idx >> 3, kq = (idx & 7) * 4;
      float4 wv = *(const float4*)&W[(size_t)c * IN_DIM + k0 + kq];
      Ws[kq + 0][c] = wv.x; Ws[kq + 1][c] = wv.y;
      Ws[kq + 2][c] = wv.z; Ws[kq + 3][c] = wv.w;
    }
    __syncthreads();
#pragma unroll
    for (int kk = 0; kk < 32; ++kk) {
      float4 a = *(const float4*)&Xs[kk][ty * 4];
      float4 bv = *(const float4*)&Ws[kk][tx * 4];
      float av[4] = {a.x, a.y, a.z, a.w};
      float bw[4] = {bv.x, bv.y, bv.z, bv.w};
#pragma unroll
      for (int r = 0; r < 4; ++r)
#pragma unroll
        for (int c = 0; c < 4; ++c) acc[r][c] += av[r] * bw[c];
    }
  }
  float4 bv = *(const float4*)&bias[tx * 4];
  float bb[4] = {bv.x, bv.y, bv.z, bv.w};
  float4 p1 = *(const float4*)&phi[tx * 4];
  float4 p2 = *(const float4*)&phi[OUT_DIM + tx * 4];
  float p1a[4] = {p1.x, p1.y, p1.z, p1.w};
  float p2a[4] = {p2.x, p2.y, p2.z, p2.w};
  float fp[4], sp_[4];
#pragma unroll
  for (int r = 0; r < 4; ++r) {
    int i = i0 + ty * 4 + r;
    float o[4];
    fp[r] = 0.f; sp_[r] = 0.f;
#pragma unroll
    for (int c = 0; c < 4; ++c) {
      o[c] = acc[r][c] + bb[c];
      Vt[(size_t)(tx * 4 + c) * N_NODES + i] = f2bf(o[c]);
      fp[r] = __builtin_fmaf(o[c], p1a[c], fp[r]);
      sp_[r] = __builtin_fmaf(o[c], p2a[c], sp_[r]);
    }
  }
#pragma unroll
  for (int o = 16; o; o >>= 1) {
#pragma unroll
    for (int r = 0; r < 4; ++r) {
      fp[r] += __shfl_xor(fp[r], o);
      sp_[r] += __shfl_xor(sp_[r], o);
    }
  }
  if (tx == 0) {
    unsigned kmax = 0;
#pragma unroll
    for (int r = 0; r < 4; ++r) {
      int i = i0 + ty * 4 + r;
      f[i] = fp[r]; s[i] = sp_[r];
      unsigned u = __float_as_uint(sp_[r]);
      unsigned key = (u & 0x80000000u) ? ~u : (u | 0x80000000u);
      kmax = max(kmax, key);
    }
    skey[ty] = kmax;
  }
  __syncthreads();
  if (t == 0) {
    unsigned kmax = skey[0];
#pragma unroll
    for (int q = 1; q < 8; ++q) kmax = max(kmax, skey[q]);
    atomicMax(smax, kmax);
  }
}

// ---------------- k3: fused mask/softmax-numerator + P@V (bf16 MFMA) ---------
// grid = 192 row-blocks x NSPLIT=8 (sp = blk&7 -> one j-slice per XCD exactly).
// BOTH operand streams staged coalesced into double-buffered LDS via
// global_load_lds width=16. Rule #21 both-sides XOR swizzle: dest linear,
// SOURCE chunk XOR'd by row, ds_read applies the same XOR.
// FIX vs r11: adj LDS read row is (w*16 + m), not m — each wave reads ITS
// 16 adjacency rows. (XOR key unchanged: (w*16+m)&15 == m.)
__global__ __launch_bounds__(256) void k3_attn(
    const int* __restrict__ adj, const unsigned short* __restrict__ Vt,
    const float* __restrict__ f, const float* __restrict__ s,
    const unsigned* __restrict__ smaxk,
    float* __restrict__ pacc, float* __restrict__ pden) {
  __shared__ float s_lds[JSPAN];                             // 6 KB
  __shared__ __align__(16) unsigned short vbuf[2][128 * TJ]; // 32 KB dbuf
  __shared__ __align__(16) int abuf[2][64 * TJ];             // 32 KB dbuf
  const int t = threadIdx.x;
  const int sp = blockIdx.x & (NSPLIT - 1);
  const int rb = blockIdx.x >> 3;
  const int j0g = sp * JSPAN;
  const int w = t >> 6, l = t & 63;
  const int m = l & 15, slot = l >> 4;
  const int row_g = rb * 64 + w * 16 + m;     // P row this lane computes
#pragma unroll
  for (int q = 0; q < 2; ++q) {
    int idx = t + q * 256;
    if (idx < JSPAN / 4)
      *(float4*)&s_lds[idx * 4] = *(const float4*)&s[j0g + idx * 4];
  }
  unsigned key = *smaxk;
  unsigned ku = (key & 0x80000000u) ? (key ^ 0x80000000u) : ~key;
  const float smaxv = __uint_as_float(ku);
  const float fi = f[row_g];
  const float xm = fi + smaxv;
  const float mrow = fmaxf(xm, NEG * xm);     // >= all sims in row (monotone lrelu)
  const float em = mrow * LOG2E;
  const int diag_g = row_g - j0g;             // local self-loop col (may be OOR)
  float dsum = 0.f;
  f32x4 acc[8] = {};                          // nt = 0..7 (full d=128 per wave)
  // ---- Vt staging (r9 mapping): row t>>3 (+32q), chunk t&7, src-XOR'd
  const int srow = t >> 3, schunk = t & 7;
  const int xsw = schunk ^ (srow & 7);
  const unsigned short* vt_src = Vt + (size_t)srow * N_NODES + j0g + xsw * 8;
  // Vt fragment read offsets (ushorts), same XOR on read side
  const int off0 = m * TJ + ((slot) ^ (m & 7)) * 8;
  const int off1 = m * TJ + ((4 + slot) ^ (m & 7)) * 8;
  // ---- adj staging: load q stages row arow+16q, chunk achk, src-XOR'd
  const int arow = t >> 4, achk = t & 15;
  const int* adj_src = adj + (size_t)(rb * 64 + arow) * N_NODES + j0g
                       + ((achk ^ arow) * 4);
  // adj read: lane (m,slot), half cc, sub u: LDS chunk kk=(8cc+2slot+u)^m
  const int akk00 = ((2 * slot) ^ m) * 4,     akk01 = ((2 * slot + 1) ^ m) * 4;
  const int akk10 = ((8 + 2 * slot) ^ m) * 4, akk11 = ((9 + 2 * slot) ^ m) * 4;

#define STAGE(BB, TT) {                                                      \
    const unsigned short* _vs = vt_src + (TT) * TJ;                          \
    unsigned short* _vd = &vbuf[BB][t * 8];                                  \
    __builtin_amdgcn_global_load_lds(_vs,                _vd,        16, 0, 0); \
    __builtin_amdgcn_global_load_lds(_vs + 32 * N_NODES, _vd + 2048, 16, 0, 0); \
    __builtin_amdgcn_global_load_lds(_vs + 64 * N_NODES, _vd + 4096, 16, 0, 0); \
    __builtin_amdgcn_global_load_lds(_vs + 96 * N_NODES, _vd + 6144, 16, 0, 0); \
    const int* _as = adj_src + (TT) * TJ;                                    \
    int* _ad = &abuf[BB][arow * 64 + achk * 4];                              \
    __builtin_amdgcn_global_load_lds(_as,                _ad,        16, 0, 0); \
    __builtin_amdgcn_global_load_lds(_as + 16 * N_NODES, _ad + 1024, 16, 0, 0); \
    __builtin_amdgcn_global_load_lds(_as + 32 * N_NODES, _ad + 2048, 16, 0, 0); \
    __builtin_amdgcn_global_load_lds(_as + 48 * N_NODES, _ad + 3072, 16, 0, 0); }

  STAGE(0, 0);

#define ITER(TT) {                                                           \
    __syncthreads();  /* drains stage(TT) issued one iter ago + ds_reads */  \
    if ((TT) + 1 < NT) STAGE(((TT) + 1) & 1, (TT) + 1);                      \
    const unsigned short* rdp = &vbuf[(TT) & 1][0];                          \
    const int* adp = &abuf[(TT) & 1][(w * 16 + m) * 64];   /* FIX: +w*16 */  \
    short8 b0[8], b1[8];                                                     \
    _Pragma("unroll")                                                        \
    for (int nt = 0; nt < 8; ++nt)                                           \
      b0[nt] = *(const short8*)(rdp + off0 + nt * 16 * TJ);                  \
    _Pragma("unroll")                                                        \
    for (int nt = 0; nt < 8; ++nt)                                           \
      b1[nt] = *(const short8*)(rdp + off1 + nt * 16 * TJ);                  \
    i32x4 aq[4];                                                             \
    aq[0] = *(const i32x4*)(adp + akk00); aq[1] = *(const i32x4*)(adp + akk01); \
    aq[2] = *(const i32x4*)(adp + akk10); aq[3] = *(const i32x4*)(adp + akk11); \
    short8 af0, af1;                                                         \
    _Pragma("unroll")                                                        \
    for (int c = 0; c < 2; ++c) {                                            \
      int jb = (TT) * TJ + 32 * c + 8 * slot;                                \
      float4 sv0 = *(const float4*)&s_lds[jb];                               \
      float4 sv1 = *(const float4*)&s_lds[jb + 4];                           \
      int av[8] = {aq[2*c].x, aq[2*c].y, aq[2*c].z, aq[2*c].w,               \
                   aq[2*c+1].x, aq[2*c+1].y, aq[2*c+1].z, aq[2*c+1].w};      \
      float sva[8] = {sv0.x, sv0.y, sv0.z, sv0.w, sv1.x, sv1.y, sv1.z, sv1.w}; \
      _Pragma("unroll")                                                      \
      for (int q = 0; q < 8; ++q) {                                          \
        float x = fi + sva[q];                                               \
        float xl = fmaxf(x, NEG * x);                                        \
        float e = fast_exp2(__builtin_fmaf(xl, LOG2E, -em));                 \
        bool edge = (av[q] > 0) || ((jb + q) == diag_g);                     \
        float p = edge ? e : 0.f;                                            \
        dsum += p;                                                           \
        if (c == 0) af0[q] = (short)f2bf(p); else af1[q] = (short)f2bf(p);   \
      }                                                                      \
    }                                                                        \
    _Pragma("unroll")                                                        \
    for (int nt = 0; nt < 8; ++nt)                                           \
      acc[nt] = __builtin_amdgcn_mfma_f32_16x16x32_bf16(af0, b0[nt], acc[nt], 0, 0, 0); \
    _Pragma("unroll")                                                        \
    for (int nt = 0; nt < 8; ++nt)                                           \
      acc[nt] = __builtin_amdgcn_mfma_f32_16x16x32_bf16(af1, b1[nt], acc[nt], 0, 0, 0); \
  }

  for (int tb = 0; tb < NT; ++tb) {
    ITER(tb);
  }
#undef ITER
#undef STAGE

  // row denominator: reduce over the 4 k-slot lanes {m, m+16, m+32, m+48}
  dsum += __shfl_xor(dsum, 16);
  dsum += __shfl_xor(dsum, 32);
  if (l < 16) pden[sp * N_NODES + rb * 64 + w * 16 + l] = dsum;
  // C write: out-row = rb*64 + 16w + slot*4 + r, out-col = nt*16 + m
  float* pa = pacc + (size_t)sp * N_NODES * OUT_DIM;
#pragma unroll
  for (int nt = 0; nt < 8; ++nt)
#pragma unroll
    for (int r = 0; r < 4; ++r) {
      int ii = rb * 64 + w * 16 + slot * 4 + r;
      pa[(size_t)ii * OUT_DIM + nt * 16 + m] = acc[nt][r];
    }
}

// ---------------- k4: combine partials, divide, final leaky_relu -------------
__global__ __launch_bounds__(256) void k4_comb(
    const float* __restrict__ pacc, const float* __restrict__ pden,
    float* __restrict__ out) {
  int idx = blockIdx.x * 256 + threadIdx.x;
  int i = idx >> 7;
  float v = 0.f, den = 0.f;
#pragma unroll
  for (int spp = 0; spp < NSPLIT; ++spp) {
    v += pacc[(size_t)spp * N_NODES * OUT_DIM + idx];
    den += pden[spp * N_NODES + i];
  }
  float o = v / den;
  out[idx] = fmaxf(o, NEG * o);
}

extern "C" void kernel_launch(void* const* d_in, const int* in_sizes, int n_in,
                              void* d_out, int out_size, void* d_ws, size_t ws_size,
                              hipStream_t stream) {
  const int* adj = (const int*)d_in[0];
  const float* X = (const float*)d_in[1];
  const float* W = (const float*)d_in[2];
  const float* b = (const float*)d_in[3];
  const float* phi = (const float*)d_in[4];
  float* out = (float*)d_out;
  char* ws = (char*)d_ws;
  // ws layout (bytes, 16-aligned):
  unsigned short* Vt = (unsigned short*)(ws);            // 128*12288*2 = 3,145,728
  float* fv   = (float*)(ws + 3145728);                  // 49,152
  float* sv   = (float*)(ws + 3194880);                  // 49,152
  unsigned* smax = (unsigned*)(ws + 3244032);            // 16
  float* pden = (float*)(ws + 3244048);                  // 8*12288*4 = 393,216
  float* pacc = (float*)(ws + 3637264);                  // 8*12288*128*4 = 50,331,648

  hipMemsetAsync(smax, 0, 4, stream);
  hipLaunchKernelGGL(k1_proj, dim3(N_NODES / 32), dim3(256), 0, stream,
                     X, W, b, phi, Vt, fv, sv, smax);
  hipLaunchKernelGGL(k3_attn, dim3((N_NODES / 64) * NSPLIT), dim3(256), 0, stream,
                     adj, Vt, fv, sv, smax, pacc, pden);
  hipLaunchKernelGGL(k4_comb, dim3((N_NODES * OUT_DIM) / 256), dim3(256), 0, stream,
                     pacc, pden, out);
}